// Round 11
// baseline (474.134 us; speedup 1.0000x reference)
//
#include <hip/hip_runtime.h>
#include <cstdint>

#define T_SEQ 40
#define NB    16384
#define NH    128
#define ZSTR  168            // bf16 elems per z-tile row (160 used)
#define MSTR  132            // padded dword stride for mask slab (kills q-group 4-way conflict)
#define GROWS 32             // batch rows per block (two 16-row M-tiles)
#define NTHR  512            // 8 waves; wave w owns neuron cols [16w, 16w+16)
#define NBLK  (NB / GROWS)   // 512 blocks -> 2 generations at 1 block/CU

typedef float v4f __attribute__((ext_vector_type(4)));
typedef short v8s __attribute__((ext_vector_type(8)));

// RNE float->bf16 bits; w == b1+b2+b3 exactly (24-bit mantissa = 3x8)
__device__ __forceinline__ unsigned short f2bf(float f) {
  uint32_t u = __float_as_uint(f);
  return (unsigned short)((u + 0x7FFFu + ((u >> 16) & 1u)) >> 16);
}
__device__ __forceinline__ float bf2f(unsigned short b) {
  return __uint_as_float(((uint32_t)b) << 16);
}
template <int C>
__device__ __forceinline__ float dppadd(float v) {
  int t = __builtin_amdgcn_update_dpp(0, __float_as_int(v), C, 0xF, 0xF, true);
  return v + __int_as_float(t);
}
__device__ __forceinline__ float red16(float v) {   // sum within each 16-lane DPP row
  v = dppadd<0x111>(v);
  v = dppadd<0x112>(v);
  v = dppadd<0x114>(v);
  v = dppadd<0x118>(v);
  return v;                                          // lane q*16+15 holds the row sum
}

__global__ __launch_bounds__(NTHR, 2)
void Policy_22033182228693_kernel(const float* __restrict__ x,
                                  const float* __restrict__ w_in,
                                  const float* __restrict__ w_rec,
                                  const float* __restrict__ w_out,
                                  const float* __restrict__ dmask,
                                  float* __restrict__ out)
{
  __shared__ unsigned short Z[2][GROWS * ZSTR];    // [z(128)|xs(8)|pad0] bf16, dbuf   (21.0 KB)
  __shared__ unsigned short XS[T_SEQ * 256];       // encoder spikes [t][row*8+ch]     (20.0 KB)
  __shared__ float MB[3][GROWS * MSTR];            // mask slabs, ring-3, prefetch d=2 (49.5 KB)
  __shared__ float UP[2][8][GROWS][2];             // per-wave readout partials, dbuf  ( 4.0 KB)

  const int tid  = threadIdx.x;
  const int wv   = tid >> 6;          // 0..7
  const int lane = tid & 63;
  const int m    = lane & 15;
  const int q    = lane >> 4;
  const int col  = wv * 16 + m;       // this lane's neuron column (one per lane-group)
  const int gb   = blockIdx.x * GROWS;
  const size_t TS = (size_t)NB * NH;

  // ---- register-resident B-frags for 16 columns: 15 v8s = 60 VGPRs ----
  v8s bfr[5][3];
#pragma unroll
  for (int c = 0; c < 5; ++c) {
    const int kb = c * 32 + q * 8;
    float w8[8];
    if (c < 4) {
      float4 wa = *(const float4*)&w_rec[col * NH + kb];
      float4 wb = *(const float4*)&w_rec[col * NH + kb + 4];
      w8[0]=wa.x; w8[1]=wa.y; w8[2]=wa.z; w8[3]=wa.w;
      w8[4]=wb.x; w8[5]=wb.y; w8[6]=wb.z; w8[7]=wb.w;
    } else if (q == 0) {                       // k = 128..135 -> w_in
      float4 wa = *(const float4*)&w_in[col * 8];
      float4 wb = *(const float4*)&w_in[col * 8 + 4];
      w8[0]=wa.x; w8[1]=wa.y; w8[2]=wa.z; w8[3]=wa.w;
      w8[4]=wb.x; w8[5]=wb.y; w8[6]=wb.z; w8[7]=wb.w;
    } else {                                   // k = 136..159 -> zero pad
#pragma unroll
      for (int j = 0; j < 8; ++j) w8[j] = 0.f;
    }
    union { v8s v; unsigned short u[8]; } f0, f1, f2;
#pragma unroll
    for (int j = 0; j < 8; ++j) {
      float w = w8[j];
      unsigned short b1 = f2bf(w);  float r1 = w - bf2f(b1);
      unsigned short b2 = f2bf(r1); float r2 = r1 - bf2f(b2);
      unsigned short b3 = f2bf(r2);
      f0.u[j] = b1; f1.u[j] = b2; f2.u[j] = b3;
    }
    bfr[c][0] = f0.v; bfr[c][1] = f1.v; bfr[c][2] = f2.v;
  }

  const float wo0 = w_out[col];        // w_out[0][col]
  const float wo1 = w_out[NH + col];   // w_out[1][col]

  // zero both z-tile buffers (incl. xs + pad) once
  for (int e = tid; e < 2 * GROWS * ZSTR; e += NTHR) ((unsigned short*)Z)[e] = 0;
  __syncthreads();

  // ---- prologue: mask slabs t=0,1 + encoder precompute ----
  const int srow = tid >> 4;               // 0..31
  const int scol = (tid & 15) * 8;         // 0..120
  {
    const float* g0 = dmask + (size_t)(gb + srow) * NH + scol;
    float4 a0 = *(const float4*)g0;
    float4 a1 = *(const float4*)(g0 + 4);
    const float* g1 = g0 + TS;
    float4 b0 = *(const float4*)g1;
    float4 b1 = *(const float4*)(g1 + 4);
    if (tid < 256) {                       // encoder: row=tid>>3 (0..31), ch=tid&7
      const int bi = tid >> 3, ch = tid & 7;
      float xv = x[(size_t)(gb + bi) * 4 + (ch & 3)];
      float cc = fmaxf(0.f, ((ch & 4) ? -50.f : 50.f) * xv);
      float ve = 0.f;
      for (int t = 0; t < T_SEQ; ++t) {
        ve += 0.1f * (cc - ve);
        unsigned short zb = 0;
        if (ve > 1.0f) { zb = 0x3F80; ve = 0.f; }
        XS[t * 256 + tid] = zb;
        if (t == 0) Z[0][bi * ZSTR + NH + ch] = zb;
      }
    }
    float* m0 = &MB[0][srow * MSTR + scol];
    *(float4*)m0 = a0;  *(float4*)(m0 + 4) = a1;
    float* m1 = &MB[1][srow * MSTR + scol];
    *(float4*)m1 = b0;  *(float4*)(m1 + 4) = b1;
  }
  __syncthreads();

  v4f iacc[2] = {{0,0,0,0},{0,0,0,0}};     // tile a: batch rows [a*16, a*16+16)
  v4f vmem[2] = {{0,0,0,0},{0,0,0,0}};
  float io = 0.f, vo = 0.f, mx = -3.0e38f; // wave-0 state: row=lane>>1, o=lane&1
  const int lrow = lane >> 1, lo = lane & 1;
  int pb = 0;

#pragma unroll 1
  for (int t = 0; t < T_SEQ; ++t) {
    // ---- prefetch mask slab t+2 (distance 2 covers HBM latency) ----
    const int tn = (t + 2 < T_SEQ) ? t + 2 : T_SEQ - 1;
    const float* gs = dmask + (size_t)tn * TS + (size_t)(gb + srow) * NH + scol;
    float4 npf0 = *(const float4*)gs;
    float4 npf1 = *(const float4*)(gs + 4);

    // ---- membrane from OLD i (C-layout: row = a*16 + q*4 + r, col) ----
    float zf[2][4];
#pragma unroll
    for (int a = 0; a < 2; ++a) {
      v4f vd = vmem[a] + 0.1f * (iacc[a] - vmem[a]);
#pragma unroll
      for (int r = 0; r < 4; ++r) {
        bool z = vd[r] > 1.0f;
        zf[a][r] = z ? 1.0f : 0.0f;
        vmem[a][r] = z ? 0.0f : vd[r];
      }
    }

    // ---- i_new = 0.8*i_old + [z|xs] @ W^T, per tile: 3 chains of 5 MFMAs ----
#pragma unroll
    for (int a = 0; a < 2; ++a) {
      const unsigned short* zrow = &Z[pb][(a * 16 + m) * ZSTR];
      v8s af[5];
#pragma unroll
      for (int c = 0; c < 5; ++c) af[c] = *(const v8s*)(zrow + c * 32 + q * 8);
      v4f s0 = 0.8f * iacc[a];
      v4f s1 = {0,0,0,0}, s2 = {0,0,0,0};
#pragma unroll
      for (int c = 0; c < 5; ++c) {
        s0 = __builtin_amdgcn_mfma_f32_16x16x32_bf16(af[c], bfr[c][0], s0, 0, 0, 0);
        s1 = __builtin_amdgcn_mfma_f32_16x16x32_bf16(af[c], bfr[c][1], s1, 0, 0, 0);
        s2 = __builtin_amdgcn_mfma_f32_16x16x32_bf16(af[c], bfr[c][2], s2, 0, 0, 0);
      }
      iacc[a] = (s0 + s1) + s2;
    }

    // ---- z_new + xs[t+1] into the other Z buffer ----
    unsigned short* zq = &Z[pb ^ 1][0];
#pragma unroll
    for (int a = 0; a < 2; ++a)
#pragma unroll
      for (int r = 0; r < 4; ++r)
        zq[(a * 16 + q * 4 + r) * ZSTR + col] = (zf[a][r] != 0.f) ? 0x3F80 : 0;
    if (t + 1 < T_SEQ && tid < 256)
      zq[(tid >> 3) * ZSTR + NH + (tid & 7)] = XS[(t + 1) * 256 + tid];

    // ---- readout partials over this wave's 16 cols ----
    {
      const float* mb = MB[t % 3];
#pragma unroll
      for (int a = 0; a < 2; ++a)
#pragma unroll
        for (int r = 0; r < 4; ++r) {
          const int row = a * 16 + q * 4 + r;
          float zd = zf[a][r] * mb[row * MSTR + col];
          float p0 = red16(zd * wo0);
          float p1 = red16(zd * wo1);
          if (m == 15) {
            UP[t & 1][wv][row][0] = p0;
            UP[t & 1][wv][row][1] = p1;
          }
        }
    }

    // ---- commit prefetched slab ----
    {
      float* mrow = &MB[(t + 2) % 3][srow * MSTR + scol];
      *(float4*)mrow = npf0;
      *(float4*)(mrow + 4) = npf1;
    }

    __syncthreads();   // one barrier per step

    // ---- wave 0: LI readout update for all 32 rows (UP dbuf makes this race-free) ----
    if (wv == 0) {
      float u = ((UP[t & 1][0][lrow][lo] + UP[t & 1][1][lrow][lo])
               + (UP[t & 1][2][lrow][lo] + UP[t & 1][3][lrow][lo]))
              + ((UP[t & 1][4][lrow][lo] + UP[t & 1][5][lrow][lo])
               + (UP[t & 1][6][lrow][lo] + UP[t & 1][7][lrow][lo]));
      float von = vo + 0.1f * (io - vo);   // uses old io
      io = 0.8f * io + u;
      vo = von;
      mx = fmaxf(mx, vo);
    }
    pb ^= 1;
  }

  // ---- softmax + store (wave 0: 32 rows x 2 outputs = 64 lanes) ----
  if (wv == 0) {
    float other = __shfl_xor(mx, 1);
    if (lo == 0) {
      float mxx = fmaxf(mx, other);
      float e0 = expf(mx - mxx), e1 = expf(other - mxx);
      float inv = 1.f / (e0 + e1);
      ((float2*)out)[gb + lrow] = make_float2(e0 * inv, e1 * inv);
    }
  }
}

extern "C" void kernel_launch(void* const* d_in, const int* in_sizes, int n_in,
                              void* d_out, int out_size, void* d_ws, size_t ws_size,
                              hipStream_t stream) {
  const float* x     = (const float*)d_in[0];
  const float* w_in  = (const float*)d_in[1];
  const float* w_rec = (const float*)d_in[2];
  const float* w_out = (const float*)d_in[3];
  const float* dmask = (const float*)d_in[4];
  float* out = (float*)d_out;

  hipLaunchKernelGGL(Policy_22033182228693_kernel, dim3(NBLK), dim3(NTHR), 0, stream,
                     x, w_in, w_rec, w_out, dmask, out);
}